// Round 4
// baseline (165.792 us; speedup 1.0000x reference)
//
#include <hip/hip_runtime.h>
#include <hip/hip_bf16.h>

typedef unsigned short u16;
typedef _Float16 f16;
typedef _Float16 h8 __attribute__((ext_vector_type(8)));
typedef float f32x4 __attribute__((ext_vector_type(4)));

#define B_   128
#define PP_  1024
#define LP_  128
#define H_   256
#define NP_  131072
#define NL_  16384
#define ASTRIDE 264    // 256 + 8 pad (f16 units)

// ---------------------------------------------------------------- merged prep
// grid 513 x 256:
//  bid 0..255  : zero ysum slice; bid<64 transpose W1 -> f16 w1t[n*256+k];
//                bid 64..241 convert embedding tables to f16.
//  bid 256..511: r = bid-256: WcP[r][j] = (1/PP) sum_n Wd2[r][n] Wa1[n][j];
//                WcL[r][j] = (1/LP) sum_n Wd2[r][n] Wa1[256+n][j]
//  bid 512     : cvec[j] = sum_n bd2[n](Wa1[n][j]+Wa1[256+n][j]) + ba1[j]
__global__ void __launch_bounds__(256) prep_m(
    const float* __restrict__ W1,
    const float* __restrict__ Ee, const float* __restrict__ Ea,
    const float* __restrict__ Eb, const float* __restrict__ El,
    const float* __restrict__ W2, const float* __restrict__ Wa1,
    const float* __restrict__ ba1, const float* __restrict__ bd2,
    f16* __restrict__ w1t, f16* __restrict__ tbl, float* __restrict__ ysum,
    float* __restrict__ wc, float* __restrict__ cvec)
{
  __shared__ float t1[32][33];
  __shared__ float wrow[256];
  const int bid = blockIdx.x, tid = threadIdx.x;
  if (bid < 256) {
    ysum[bid * 256 + tid] = 0.f;
    if (bid < 64) {
      const int bx = (bid & 7) * 32, by = (bid >> 3) * 32;
      const int lx = tid & 31, ly = tid >> 5;
#pragma unroll
      for (int r = 0; r < 32; r += 8)
        t1[ly + r][lx] = W1[(by + ly + r) * 256 + bx + lx];
      __syncthreads();
#pragma unroll
      for (int r = 0; r < 32; r += 8)
        w1t[(bx + ly + r) * 256 + by + lx] = (f16)t1[lx][ly + r];
    } else if (bid < 242) {
      const int idx = (bid - 64) * 256 + tid;   // 178 blocks cover exactly 45568
      float v;
      if (idx < 32768)      v = Ee[idx];
      else if (idx < 40960) v = Ea[idx - 32768];
      else if (idx < 41472) v = Eb[idx - 40960];
      else                  v = El[idx - 41472];
      tbl[idx] = (f16)v;
    }
  } else if (bid < 512) {
    const int r = bid - 256;
    wrow[tid] = W2[r * 256 + tid];
    __syncthreads();
    float aP0 = 0.f, aP1 = 0.f, aL0 = 0.f, aL1 = 0.f;
#pragma unroll 4
    for (int n = 0; n < 256; n += 2) {
      float w0 = wrow[n], w1 = wrow[n + 1];
      aP0 += w0 * Wa1[n * 256 + tid];
      aP1 += w1 * Wa1[(n + 1) * 256 + tid];
      aL0 += w0 * Wa1[(256 + n) * 256 + tid];
      aL1 += w1 * Wa1[(257 + n) * 256 + tid];
    }
    wc[r * 256 + tid]         = (aP0 + aP1) * (1.f / (float)PP_);
    wc[65536 + r * 256 + tid] = (aL0 + aL1) * (1.f / (float)LP_);
  } else {
    float a = ba1[tid];
#pragma unroll 8
    for (int n = 0; n < 256; ++n)
      a += bd2[n] * (Wa1[n * 256 + tid] + Wa1[(256 + n) * 256 + tid]);
    cvec[tid] = a;
  }
}

// ---------------------------------------------------------------- GEMM1 + silu + batch colsum
// Block = (batch, s): tiles s, s+9, s+18, s+27 of this batch's 36 (32 P + 4 L).
// Pool column-sums accumulate in registers across tiles; one shuffle+atomic
// round per block. Bias folded into MFMA C-init. Double-buffered LDS A-tile
// with register prefetch of the next tile's gathers.
__global__ void __launch_bounds__(256, 2) mlp1pool_k(
    const int* __restrict__ pel, const int* __restrict__ paa,
    const int* __restrict__ pbb, const int* __restrict__ ltyp,
    const f16* __restrict__ tbl, const f16* __restrict__ w1t,
    const float* __restrict__ bd1, float* __restrict__ ysum)
{
  __shared__ __attribute__((aligned(16))) f16 ldsA[2][32 * ASTRIDE];  // 33 KB
  const f16* Te = tbl;
  const f16* Ta = tbl + 32768;
  const f16* Tb = tbl + 40960;
  const f16* Tl = tbl + 41472;

  const int tid = threadIdx.x;
  const int wave = tid >> 6, lane = tid & 63;
  const int l15 = lane & 15, quad = lane >> 4;
  const int n0 = wave * 64;
  const int srow = tid >> 3, scp = tid & 7;  // staging: 8 threads/row, 32 k each
  const int batch = blockIdx.x / 9, s = blockIdx.x % 9;

  // resident weights: 32 frags x 16 B = 128 VGPRs
  h8 Breg[32];
#pragma unroll
  for (int t = 0; t < 4; ++t)
#pragma unroll
    for (int ks = 0; ks < 8; ++ks)
      Breg[t * 8 + ks] = *(const h8*)(w1t + (n0 + t * 16 + l15) * 256 + ks * 32 + quad * 8);

  float bias[4];
#pragma unroll
  for (int t = 0; t < 4; ++t) bias[t] = bd1[n0 + t * 16 + l15];

  float accP[4] = {0.f, 0.f, 0.f, 0.f};
  float accL[4] = {0.f, 0.f, 0.f, 0.f};

  auto fetchv = [&](int li, h8* v) {
    if (li < 32) {
      const int grow = batch * PP_ + li * 32 + srow;
      const h8* s0 = (const h8*)(Te + pel[grow] * 256 + scp * 32);
      const h8* s1 = (const h8*)(Ta + paa[grow] * 256 + scp * 32);
      const h8* s2 = (const h8*)(Tb + pbb[grow] * 256 + scp * 32);
#pragma unroll
      for (int c = 0; c < 4; ++c) v[c] = s0[c] + s1[c] + s2[c];
    } else {
      const int lrow = batch * LP_ + (li - 32) * 32 + srow;
      const h8* s0 = (const h8*)(Tl + ltyp[lrow] * 256 + scp * 32);
#pragma unroll
      for (int c = 0; c < 4; ++c) v[c] = s0[c];
    }
  };

  h8 v[4];
  fetchv(s, v);
#pragma unroll
  for (int c = 0; c < 4; ++c)
    *(h8*)(ldsA[0] + srow * ASTRIDE + scp * 32 + c * 8) = v[c];

  int buf = 0;
#pragma unroll 1
  for (int it = 0; it < 4; ++it, buf ^= 1) {
    const int li = s + it * 9;
    const bool more = it < 3;
    __syncthreads();   // ldsA[buf] fully staged / prev reads done

    h8 vn[4];
    if (more) fetchv(li + 9, vn);   // gathers in flight during MFMA

    f32x4 acc[8];
#pragma unroll
    for (int t = 0; t < 4; ++t) {
      acc[t]     = (f32x4){bias[t], bias[t], bias[t], bias[t]};
      acc[4 + t] = acc[t];
    }

#pragma unroll
    for (int ks = 0; ks < 8; ++ks) {
      h8 a0 = *(const h8*)(ldsA[buf] + l15 * ASTRIDE + ks * 32 + quad * 8);
      h8 a1 = *(const h8*)(ldsA[buf] + (16 + l15) * ASTRIDE + ks * 32 + quad * 8);
#pragma unroll
      for (int t = 0; t < 4; ++t) {
        acc[t]     = __builtin_amdgcn_mfma_f32_16x16x32_f16(a0, Breg[t * 8 + ks], acc[t], 0, 0, 0);
        acc[4 + t] = __builtin_amdgcn_mfma_f32_16x16x32_f16(a1, Breg[t * 8 + ks], acc[4 + t], 0, 0, 0);
      }
    }

    if (more) {
#pragma unroll
      for (int c = 0; c < 4; ++c)
        *(h8*)(ldsA[buf ^ 1] + srow * ASTRIDE + scp * 32 + c * 8) = vn[c];
    }

    // epilogue: silu + in-lane colsum (8 rows), accumulate in registers
    const bool isP = li < 32;
#pragma unroll
    for (int t = 0; t < 4; ++t) {
      float sum = 0.f;
#pragma unroll
      for (int mi = 0; mi < 2; ++mi)
#pragma unroll
        for (int r = 0; r < 4; ++r) {
          float pre = acc[mi * 4 + t][r];
          sum += pre * __builtin_amdgcn_rcpf(1.f + __expf(-pre));
        }
      if (isP) accP[t] += sum; else accL[t] += sum;
    }
  }

  // one cross-lane reduce + atomic round per block
  float* poolP = ysum + batch * 256;
  float* poolL = ysum + 32768 + batch * 256;
#pragma unroll
  for (int t = 0; t < 4; ++t) {
    float sp = accP[t];
    sp += __shfl_xor(sp, 16);
    sp += __shfl_xor(sp, 32);
    if (lane < 16) atomicAdd(poolP + n0 + t * 16 + lane, sp);
  }
  if (s >= 5) {   // only these blocks own an L tile
#pragma unroll
    for (int t = 0; t < 4; ++t) {
      float sl = accL[t];
      sl += __shfl_xor(sl, 16);
      sl += __shfl_xor(sl, 32);
      if (lane < 16) atomicAdd(poolL + n0 + t * 16 + lane, sl);
    }
  }
}

// ---------------------------------------------------------------- head: contact + collapsed matvec
// One 1024-thread block per batch. Contact: 8 threads/ligand from padded LDS.
// pre[j] = ysumP@WcP + ysumL@WcL + cvec + c0*Wa1[512] + c1*Wa1[513];
// out = silu(pre)@Wa2 + ba2. Matvec K=512 split across 4 thread-groups, 8 accs.
__global__ void __launch_bounds__(1024) head_k(
    const float* __restrict__ ppos, const float* __restrict__ lpos,
    const float* __restrict__ ysum, const float* __restrict__ wc,
    const float* __restrict__ cvec, const float* __restrict__ Wa1,
    const float* __restrict__ Wa2, const float* __restrict__ ba2,
    float* __restrict__ out)
{
  __shared__ float px[8 * 132], py[8 * 132], pz[8 * 132];  // 8 segs of 128 + 4 pad
  __shared__ float ysc[512];
  __shared__ float part[1024];
  __shared__ float lmin[128];
  __shared__ float cls[2];
  __shared__ float red[4];
  const int b = blockIdx.x, tid = threadIdx.x;

  {
    const int d = (tid >> 7) * 132 + (tid & 127);
    const float* p = ppos + ((size_t)b * PP_ + tid) * 3;
    px[d] = p[0]; py[d] = p[1]; pz[d] = p[2];
  }
  if (tid < 512)
    ysc[tid] = (tid < 256) ? ysum[b * 256 + tid]
                           : ysum[32768 + b * 256 + (tid - 256)];
  __syncthreads();

  // contact: 8 threads per ligand, 128 points each, float4 LDS reads
  {
    const int lig = tid >> 3, prt = tid & 7;
    const float* lp = lpos + ((size_t)b * LP_ + lig) * 3;
    const float lx = lp[0], ly = lp[1], lz = lp[2];
    const float4* X4 = (const float4*)(px + prt * 132);
    const float4* Y4 = (const float4*)(py + prt * 132);
    const float4* Z4 = (const float4*)(pz + prt * 132);
    float m = 3.4e38f;
#pragma unroll 8
    for (int i = 0; i < 32; ++i) {
      float4 X = X4[i], Y = Y4[i], Z = Z4[i];
      float dx, dy, dz, d2;
      dx = lx - X.x; dy = ly - Y.x; dz = lz - Z.x;
      d2 = dx * dx + dy * dy + dz * dz; m = fminf(m, d2);
      dx = lx - X.y; dy = ly - Y.y; dz = lz - Z.y;
      d2 = dx * dx + dy * dy + dz * dz; m = fminf(m, d2);
      dx = lx - X.z; dy = ly - Y.z; dz = lz - Z.z;
      d2 = dx * dx + dy * dy + dz * dz; m = fminf(m, d2);
      dx = lx - X.w; dy = ly - Y.w; dz = lz - Z.w;
      d2 = dx * dx + dy * dy + dz * dz; m = fminf(m, d2);
    }
    m = fminf(m, __shfl_xor(m, 1));
    m = fminf(m, __shfl_xor(m, 2));
    m = fminf(m, __shfl_xor(m, 4));
    if (prt == 0) lmin[lig] = sqrtf(m);
  }
  __syncthreads();
  if (tid < 64) {
    const float a0 = lmin[tid], a1 = lmin[tid + 64];
    float sm = a0 + a1, mn = fminf(a0, a1);
#pragma unroll
    for (int off = 32; off; off >>= 1) {
      sm += __shfl_down(sm, off);
      mn = fminf(mn, __shfl_down(mn, off));
    }
    if (tid == 0) { cls[0] = sm * (1.f / (float)LP_); cls[1] = mn; }
  }

  // matvec partials: group g covers k in [g*128, g*128+128), thread = output col
  {
    const int g = tid >> 8, j = tid & 255;
    const int kbase = g * 128;
    const float* W = wc + (g >> 1) * 65536 + (kbase & 255) * 256 + j;
    const float* ys = ysc + kbase;
    float a[8];
#pragma unroll
    for (int u = 0; u < 8; ++u) a[u] = 0.f;
#pragma unroll 2
    for (int k = 0; k < 128; k += 8) {
#pragma unroll
      for (int u = 0; u < 8; ++u)
        a[u] += ys[k + u] * W[(k + u) * 256];
    }
    part[tid] = ((a[0] + a[1]) + (a[2] + a[3])) + ((a[4] + a[5]) + (a[6] + a[7]));
  }
  __syncthreads();

  if (tid < 256) {
    float pre = (part[tid] + part[256 + tid]) + (part[512 + tid] + part[768 + tid])
              + cvec[tid]
              + cls[0] * Wa1[512 * 256 + tid] + cls[1] * Wa1[513 * 256 + tid];
    float si = pre * __builtin_amdgcn_rcpf(1.f + __expf(-pre));
    float p = si * Wa2[tid];
#pragma unroll
    for (int off = 32; off; off >>= 1) p += __shfl_down(p, off);
    if ((tid & 63) == 0) red[tid >> 6] = p;
  }
  __syncthreads();
  if (tid == 0) out[b] = (red[0] + red[1]) + (red[2] + red[3]) + ba2[0];
}

// ---------------------------------------------------------------- launch
extern "C" void kernel_launch(void* const* d_in, const int* in_sizes, int n_in,
                              void* d_out, int out_size, void* d_ws, size_t ws_size,
                              hipStream_t stream)
{
  const float* protein_pos = (const float*)d_in[0];
  const float* ligand_pos  = (const float*)d_in[1];
  const int*   pel  = (const int*)d_in[2];
  const int*   paa  = (const int*)d_in[3];
  const int*   pbb  = (const int*)d_in[4];
  const int*   ltyp = (const int*)d_in[5];
  const float* Ee  = (const float*)d_in[8];
  const float* Ea  = (const float*)d_in[9];
  const float* Eb  = (const float*)d_in[10];
  const float* El  = (const float*)d_in[11];
  const float* Wd1 = (const float*)d_in[12];
  const float* bd1 = (const float*)d_in[13];
  const float* Wd2 = (const float*)d_in[14];
  const float* bd2 = (const float*)d_in[15];
  const float* Wa1 = (const float*)d_in[16];
  const float* ba1 = (const float*)d_in[17];
  const float* Wa2 = (const float*)d_in[18];
  const float* ba2 = (const float*)d_in[19];
  float* out = (float*)d_out;

  char* ws = (char*)d_ws;
  f16*   w1t  = (f16*)(ws);                  // 131072 B
  f16*   tbl  = (f16*)(ws + 131072);         // 91136 B
  float* ysum = (float*)(ws + 262144);       // 262144 B (P pools | L pools)
  float* wc   = (float*)(ws + 524288);       // 524288 B (WcP | WcL)
  float* cvec = (float*)(ws + 1048576);      // 1024 B

  prep_m<<<513, 256, 0, stream>>>(Wd1, Ee, Ea, Eb, El, Wd2, Wa1, ba1, bd2,
                                  w1t, tbl, ysum, wc, cvec);
  mlp1pool_k<<<1152, 256, 0, stream>>>(pel, paa, pbb, ltyp, tbl, w1t, bd1, ysum);
  head_k<<<B_, 1024, 0, stream>>>(protein_pos, ligand_pos, ysum, wc, cvec,
                                  Wa1, Wa2, ba2, out);
}

// Round 5
// 139.948 us; speedup vs baseline: 1.1847x; 1.1847x over previous
//
#include <hip/hip_runtime.h>
#include <hip/hip_bf16.h>

typedef _Float16 f16;
typedef _Float16 h4 __attribute__((ext_vector_type(4)));
typedef float f32x4 __attribute__((ext_vector_type(4)));

#define B_   128
#define PP_  1024
#define LP_  128
#define H_   256
#define NP_  131072
#define NL_  16384

// Projected-table row layout in tbl (f16, 178 rows x 256):
//   PE rows 0..127   = Ee@Wd1
//   PA rows 128..159 = Ea@Wd1
//   PB rows 160..161 = Eb@Wd1 + bd1
//   PL rows 162..177 = El@Wd1 + bd1

// ---------------------------------------------------------------- prep
// grid 691 x 256:
//  bid 0..177  : projected table row (dot of one embedding row with Wd1 cols)
//  bid 178..689: r=bid-178: wc row — WcP[r][j]=(1/PP) sum_n Wd2[r][n]Wa1[n][j]
//                (half=0) or WcL with Wa1[256+n] (half=1, 1/LP)
//  bid 690     : cvec[j] = ba1[j] + sum_n bd2[n](Wa1[n][j]+Wa1[256+n][j])
//  bid 0..255 additionally zero ysum.
__global__ void __launch_bounds__(256) prep_k(
    const float* __restrict__ W1,
    const float* __restrict__ Ee, const float* __restrict__ Ea,
    const float* __restrict__ Eb, const float* __restrict__ El,
    const float* __restrict__ bd1, const float* __restrict__ W2,
    const float* __restrict__ Wa1, const float* __restrict__ ba1,
    const float* __restrict__ bd2,
    f16* __restrict__ tbl, float* __restrict__ wc, float* __restrict__ cvec,
    float* __restrict__ ysum)
{
  __shared__ float src[256];
  const int bid = blockIdx.x, tid = threadIdx.x;
  if (bid < 256) ysum[bid * 256 + tid] = 0.f;

  if (bid < 178) {
    const float* s;
    float badd = 0.f;
    if (bid < 128)      s = Ee + bid * 256;
    else if (bid < 160) s = Ea + (bid - 128) * 256;
    else if (bid < 162) { s = Eb + (bid - 160) * 256; badd = bd1[tid]; }
    else                { s = El + (bid - 162) * 256; badd = bd1[tid]; }
    src[tid] = s[tid];
    __syncthreads();
    float a0 = 0.f, a1 = 0.f, a2 = 0.f, a3 = 0.f;
#pragma unroll 4
    for (int k = 0; k < 256; k += 4) {
      a0 += src[k]     * W1[(k)     * 256 + tid];
      a1 += src[k + 1] * W1[(k + 1) * 256 + tid];
      a2 += src[k + 2] * W1[(k + 2) * 256 + tid];
      a3 += src[k + 3] * W1[(k + 3) * 256 + tid];
    }
    tbl[bid * 256 + tid] = (f16)(((a0 + a1) + (a2 + a3)) + badd);
  } else if (bid < 690) {
    const int r = bid - 178;
    const int half = r >> 8, rr = r & 255;
    src[tid] = W2[rr * 256 + tid];
    __syncthreads();
    const float* W = Wa1 + half * 256 * 256 + tid;
    float a0 = 0.f, a1 = 0.f, a2 = 0.f, a3 = 0.f;
#pragma unroll 4
    for (int n = 0; n < 256; n += 4) {
      a0 += src[n]     * W[(n)     * 256];
      a1 += src[n + 1] * W[(n + 1) * 256];
      a2 += src[n + 2] * W[(n + 2) * 256];
      a3 += src[n + 3] * W[(n + 3) * 256];
    }
    const float scale = half ? (1.f / (float)LP_) : (1.f / (float)PP_);
    wc[half * 65536 + rr * 256 + tid] = ((a0 + a1) + (a2 + a3)) * scale;
  } else {
    float a = ba1[tid];
#pragma unroll 8
    for (int n = 0; n < 256; ++n)
      a += bd2[n] * (Wa1[n * 256 + tid] + Wa1[(256 + n) * 256 + tid]);
    cvec[tid] = a;
  }
}

// ---------------------------------------------------------------- gather + silu + batch colsum
// No MFMA, no weight traffic: y1_pre[row] = PE[el]+PA[aa]+PB[bb] (or PL[type]),
// pooled via register colsum. Block = (batch, g in 0..17): g<16 protein 64-row
// group, g>=16 ligand 64-row group. Wave handles 16 rows; lane owns 4 cols.
__global__ void __launch_bounds__(256, 4) gpool_k(
    const int* __restrict__ pel, const int* __restrict__ paa,
    const int* __restrict__ pbb, const int* __restrict__ ltyp,
    const f16* __restrict__ tbl, float* __restrict__ ysum)
{
  const int tid = threadIdx.x, wave = tid >> 6, lane = tid & 63;
  const int batch = blockIdx.x / 18, g = blockIdx.x % 18;
  const int c0 = lane * 4;
  f32x4 acc = (f32x4){0.f, 0.f, 0.f, 0.f};

  if (g < 16) {
    const int base = batch * PP_ + g * 64 + wave * 16;
#pragma unroll 4
    for (int r = 0; r < 16; ++r) {
      const int idx = base + r;
      h4 va = *(const h4*)(tbl + pel[idx] * 256 + c0);
      h4 vb = *(const h4*)(tbl + 32768 + paa[idx] * 256 + c0);
      h4 vc = *(const h4*)(tbl + 40960 + pbb[idx] * 256 + c0);
#pragma unroll
      for (int i = 0; i < 4; ++i) {
        float pre = (float)va[i] + (float)vb[i] + (float)vc[i];
        acc[i] += pre * __builtin_amdgcn_rcpf(1.f + __expf(-pre));
      }
    }
  } else {
    const int base = batch * LP_ + (g - 16) * 64 + wave * 16;
#pragma unroll 4
    for (int r = 0; r < 16; ++r) {
      const int idx = base + r;
      h4 v = *(const h4*)(tbl + 41472 + ltyp[idx] * 256 + c0);
#pragma unroll
      for (int i = 0; i < 4; ++i) {
        float pre = (float)v[i];
        acc[i] += pre * __builtin_amdgcn_rcpf(1.f + __expf(-pre));
      }
    }
  }

  __shared__ f32x4 red[3][64];
  if (wave) red[wave - 1][lane] = acc;
  __syncthreads();
  if (wave == 0) {
    f32x4 a1 = red[0][lane], a2 = red[1][lane], a3 = red[2][lane];
    float* pool = ysum + (g < 16 ? 0 : 32768) + batch * 256 + c0;
#pragma unroll
    for (int i = 0; i < 4; ++i)
      atomicAdd(pool + i, ((acc[i] + a1[i]) + (a2[i] + a3[i])));
  }
}

// ---------------------------------------------------------------- head: contact + collapsed matvec
// One 512-thread block per batch.
// pre[j] = ysumP@WcP + ysumL@WcL + cvec + c0*Wa1[512] + c1*Wa1[513];
// out = silu(pre)@Wa2 + ba2.
__global__ void __launch_bounds__(512) head_k(
    const float* __restrict__ ppos, const float* __restrict__ lpos,
    const float* __restrict__ ysum, const float* __restrict__ wc,
    const float* __restrict__ cvec, const float* __restrict__ Wa1,
    const float* __restrict__ Wa2, const float* __restrict__ ba2,
    float* __restrict__ out)
{
  __shared__ float px[4 * 264], py[4 * 264], pz[4 * 264];  // 4 segs of 256 (+8 pad)
  __shared__ float ysc[512];
  __shared__ float part[512];
  __shared__ float lmin[128];
  __shared__ float cls[2];
  __shared__ float red[4];
  const int b = blockIdx.x, tid = threadIdx.x;

#pragma unroll
  for (int r = 0; r < 2; ++r) {
    const int i = r * 512 + tid;            // 0..1023
    const int d = (i >> 8) * 264 + (i & 255);
    const float* p = ppos + ((size_t)b * PP_ + i) * 3;
    px[d] = p[0]; py[d] = p[1]; pz[d] = p[2];
  }
  ysc[tid] = (tid < 256) ? ysum[b * 256 + tid]
                         : ysum[32768 + b * 256 + (tid - 256)];
  __syncthreads();

  // contact: 4 threads per ligand, 256 points each, float4 LDS reads
  {
    const int lig = tid >> 2, prt = tid & 3;
    const float* lp = lpos + ((size_t)b * LP_ + lig) * 3;
    const float lx = lp[0], ly = lp[1], lz = lp[2];
    const float4* X4 = (const float4*)(px + prt * 264);
    const float4* Y4 = (const float4*)(py + prt * 264);
    const float4* Z4 = (const float4*)(pz + prt * 264);
    float m = 3.4e38f;
#pragma unroll 4
    for (int i = 0; i < 64; ++i) {
      float4 X = X4[i], Y = Y4[i], Z = Z4[i];
      float dx, dy, dz, d2;
      dx = lx - X.x; dy = ly - Y.x; dz = lz - Z.x;
      d2 = dx * dx + dy * dy + dz * dz; m = fminf(m, d2);
      dx = lx - X.y; dy = ly - Y.y; dz = lz - Z.y;
      d2 = dx * dx + dy * dy + dz * dz; m = fminf(m, d2);
      dx = lx - X.z; dy = ly - Y.z; dz = lz - Z.z;
      d2 = dx * dx + dy * dy + dz * dz; m = fminf(m, d2);
      dx = lx - X.w; dy = ly - Y.w; dz = lz - Z.w;
      d2 = dx * dx + dy * dy + dz * dz; m = fminf(m, d2);
    }
    m = fminf(m, __shfl_xor(m, 1));
    m = fminf(m, __shfl_xor(m, 2));
    if (prt == 0) lmin[lig] = sqrtf(m);
  }
  __syncthreads();
  if (tid < 64) {
    const float a0 = lmin[tid], a1 = lmin[tid + 64];
    float sm = a0 + a1, mn = fminf(a0, a1);
#pragma unroll
    for (int off = 32; off; off >>= 1) {
      sm += __shfl_down(sm, off);
      mn = fminf(mn, __shfl_down(mn, off));
    }
    if (tid == 0) { cls[0] = sm * (1.f / (float)LP_); cls[1] = mn; }
  }

  // matvec partials: group g covers k-half, thread = output col
  {
    const int gg = tid >> 8, j = tid & 255;
    const float* W = wc + gg * 65536 + j;
    const float* ys = ysc + gg * 256;
    float a[8];
#pragma unroll
    for (int u = 0; u < 8; ++u) a[u] = 0.f;
#pragma unroll 2
    for (int k = 0; k < 256; k += 8) {
#pragma unroll
      for (int u = 0; u < 8; ++u)
        a[u] += ys[k + u] * W[(k + u) * 256];
    }
    part[tid] = ((a[0] + a[1]) + (a[2] + a[3])) + ((a[4] + a[5]) + (a[6] + a[7]));
  }
  __syncthreads();

  if (tid < 256) {
    float pre = part[tid] + part[256 + tid] + cvec[tid]
              + cls[0] * Wa1[512 * 256 + tid] + cls[1] * Wa1[513 * 256 + tid];
    float si = pre * __builtin_amdgcn_rcpf(1.f + __expf(-pre));
    float p = si * Wa2[tid];
#pragma unroll
    for (int off = 32; off; off >>= 1) p += __shfl_down(p, off);
    if ((tid & 63) == 0) red[tid >> 6] = p;
  }
  __syncthreads();
  if (tid == 0) out[b] = (red[0] + red[1]) + (red[2] + red[3]) + ba2[0];
}

// ---------------------------------------------------------------- launch
extern "C" void kernel_launch(void* const* d_in, const int* in_sizes, int n_in,
                              void* d_out, int out_size, void* d_ws, size_t ws_size,
                              hipStream_t stream)
{
  const float* protein_pos = (const float*)d_in[0];
  const float* ligand_pos  = (const float*)d_in[1];
  const int*   pel  = (const int*)d_in[2];
  const int*   paa  = (const int*)d_in[3];
  const int*   pbb  = (const int*)d_in[4];
  const int*   ltyp = (const int*)d_in[5];
  const float* Ee  = (const float*)d_in[8];
  const float* Ea  = (const float*)d_in[9];
  const float* Eb  = (const float*)d_in[10];
  const float* El  = (const float*)d_in[11];
  const float* Wd1 = (const float*)d_in[12];
  const float* bd1 = (const float*)d_in[13];
  const float* Wd2 = (const float*)d_in[14];
  const float* bd2 = (const float*)d_in[15];
  const float* Wa1 = (const float*)d_in[16];
  const float* ba1 = (const float*)d_in[17];
  const float* Wa2 = (const float*)d_in[18];
  const float* ba2 = (const float*)d_in[19];
  float* out = (float*)d_out;

  char* ws = (char*)d_ws;
  f16*   tbl  = (f16*)(ws);                  // 178*256 f16 = 91136 B
  float* ysum = (float*)(ws + 98304);        // 65536 f32 = 262144 B
  float* wc   = (float*)(ws + 360448);       // 131072 f32 = 524288 B
  float* cvec = (float*)(ws + 884736);       // 1024 B

  prep_k<<<691, 256, 0, stream>>>(Wd1, Ee, Ea, Eb, El, bd1, Wd2, Wa1, ba1, bd2,
                                  tbl, wc, cvec, ysum);
  gpool_k<<<B_ * 18, 256, 0, stream>>>(pel, paa, pbb, ltyp, tbl, ysum);
  head_k<<<B_, 512, 0, stream>>>(protein_pos, ligand_pos, ysum, wc, cvec,
                                 Wa1, Wa2, ba2, out);
}